// Round 4
// baseline (307.328 us; speedup 1.0000x reference)
//
#include <hip/hip_runtime.h>
#include <hip/hip_bf16.h>
#include <math.h>

// CrossGeometricStructureEmbedding, round 4.
// R3 post-mortem: launch_bounds(256,3) + manual double-prefetch => scratch
// spill (FETCH 227MB/WRITE 84MB = spill traffic). R4 keeps B-streaming from
// L2 but with a register-lean ks-outer loop (live: 64 acc + 16 bw + 16 afr),
// fuses BOTH embedding types into one block (no atomics, no memset), and uses
// grid=1024 (P_PTS=4) + 35KB LDS so 3 blocks/CU are resident.
// Per point: fill E(d) -> sync -> d-GEMM (geom(q+1) overlapped) -> sync ->
// fill E(a) -> sync -> a-GEMM -> store(dmx+amx+bias) -> sync.

typedef __attribute__((ext_vector_type(8))) short short8;
typedef __attribute__((ext_vector_type(4))) float f32x4;
typedef __attribute__((ext_vector_type(4))) unsigned int uint4v;

#define HH 256
#define P_PTS 4
#define NPTS 4096

__device__ __forceinline__ unsigned short f2bf(float f) {
    union { float f; unsigned int u; } v; v.f = f;
    unsigned int r = v.u + 0x7fffu + ((v.u >> 16) & 1u);  // RNE
    return (unsigned short)(r >> 16);
}

__device__ __forceinline__ unsigned int pack_sc(float s, float c) {
    union { __hip_bfloat162 h; unsigned int u; } v;
    v.h = __float22bfloat162_rn(make_float2(s, c));  // low = sin, high = cos
    return v.u;
}

__global__ __launch_bounds__(256)
void prep_w_kernel(const float* __restrict__ Wa, const float* __restrict__ Wd,
                   unsigned short* __restrict__ wbf) {
    int i = blockIdx.x * 256 + threadIdx.x;
    if (i < HH * HH) {
        wbf[i] = f2bf(Wd[i]);             // [0, 65536): Wd bf16
        wbf[HH * HH + i] = f2bf(Wa[i]);   // [65536, 131072): Wa bf16
    }
}

__global__ __launch_bounds__(256, 3)
void cgse_main(const float* __restrict__ points,
               const float* __restrict__ anchors,
               const unsigned short* __restrict__ wbf,
               const float* __restrict__ ba,
               const float* __restrict__ bd,
               float* __restrict__ out) {
    __shared__ __align__(16) unsigned short E[64][264];  // 33.8 KB single buf
    __shared__ float xsd[2][64], xsa[2][64];
    __shared__ float anch[192];

    const int tid = threadIdx.x;
    const int wave = tid >> 6, lane = tid & 63;
    const int quad = lane >> 4, l16 = lane & 15;
    const int base = blockIdx.x * P_PTS;

    const unsigned short* wdp = wbf + (wave * 64 + l16) * HH + quad * 8;            // Wd strip
    const unsigned short* wap = wbf + HH * HH + (wave * 64 + l16) * HH + quad * 8;  // Wa strip

    float bias[4];
    #pragma unroll
    for (int nt = 0; nt < 4; ++nt) {
        const int c = wave * 64 + nt * 16 + l16;
        bias[nt] = ba[c] + bd[c];
    }

    // div_term split: pair index i = ks*16 + quad*4 + j
    // dt0[j] = 10000^(-(quad*4+j)/128); rk[ks] = 10000^(-ks/8)
    float dt0[4];
    #pragma unroll
    for (int j = 0; j < 4; ++j)
        dt0[j] = __expf(-(float)(quad * 4 + j) * 0.0719557841560639f);
    const float rk[8] = {1.0f, 0.31622776601683794f, 0.1f, 0.031622776601683794f,
                         0.01f, 0.0031622776601683794f, 0.001f, 0.00031622776601683794f};

    auto geom = [&](int pn, int slot) {
        if (tid < 64) {
            const float px = points[pn * 3 + 0], py = points[pn * 3 + 1], pz = points[pn * 3 + 2];
            const int k = tid, k2 = (tid + 1) & 63;  // roll(-1)
            const float r1x = px - anch[k * 3 + 0];
            const float r1y = py - anch[k * 3 + 1];
            const float r1z = pz - anch[k * 3 + 2];
            const float r2x = px - anch[k2 * 3 + 0];
            const float r2y = py - anch[k2 * 3 + 1];
            const float r2z = pz - anch[k2 * 3 + 2];
            xsd[slot][k] = sqrtf(r1x * r1x + r1y * r1y + r1z * r1z) * 5.0f;  // /SIGMA_D
            const float cx = r1y * r2z - r1z * r2y;
            const float cy = r1z * r2x - r1x * r2z;
            const float cz = r1x * r2y - r1y * r2x;
            const float sv = sqrtf(cx * cx + cy * cy + cz * cz);
            const float cv = r1x * r2x + r1y * r2y + r1z * r2z;
            xsa[slot][k] = atan2f(sv, cv) * 3.8197186342054885f;  // *180/(15*pi)
        }
    };

    const int frow = wave * 16 + l16;  // row this thread fills / A-frag row

    auto fill = [&](float xv) {
        float xq[4];
        #pragma unroll
        for (int j = 0; j < 4; ++j) xq[j] = xv * dt0[j];
        #pragma unroll
        for (int ks = 0; ks < 8; ++ks) {
            uint4v w;
            #pragma unroll
            for (int j = 0; j < 4; ++j) {
                float s, c;
                __sincosf(xq[j] * rk[ks], &s, &c);
                w[j] = pack_sc(s, c);
            }
            *(uint4v*)&E[frow][ks * 32 + quad * 8] = w;
        }
    };

    // GEMM over current E vs W strip (streamed from L2), col-max into mx[4].
    auto gemm_max = [&](const unsigned short* __restrict__ wb, float* mx) {
        f32x4 acc[4][4];
        #pragma unroll
        for (int mt = 0; mt < 4; ++mt)
            #pragma unroll
            for (int nt = 0; nt < 4; ++nt)
                acc[mt][nt] = (f32x4){0.f, 0.f, 0.f, 0.f};
        #pragma unroll
        for (int ks = 0; ks < 8; ++ks) {
            short8 bw[4];
            #pragma unroll
            for (int nt = 0; nt < 4; ++nt)
                bw[nt] = *(const short8*)(wb + nt * 16 * HH + ks * 32);
            short8 afr[4];
            #pragma unroll
            for (int mt = 0; mt < 4; ++mt)
                afr[mt] = *(const short8*)&E[mt * 16 + l16][ks * 32 + quad * 8];
            #pragma unroll
            for (int nt = 0; nt < 4; ++nt)
                #pragma unroll
                for (int mt = 0; mt < 4; ++mt)
                    acc[mt][nt] = __builtin_amdgcn_mfma_f32_16x16x32_bf16(
                        afr[mt], bw[nt], acc[mt][nt], 0, 0, 0);
        }
        #pragma unroll
        for (int nt = 0; nt < 4; ++nt) {
            float m = fmaxf(fmaxf(acc[0][nt][0], acc[0][nt][1]),
                            fmaxf(acc[0][nt][2], acc[0][nt][3]));
            #pragma unroll
            for (int mt = 1; mt < 4; ++mt)
                m = fmaxf(m, fmaxf(fmaxf(acc[mt][nt][0], acc[mt][nt][1]),
                                   fmaxf(acc[mt][nt][2], acc[mt][nt][3])));
            m = fmaxf(m, __shfl_down(m, 32));
            m = fmaxf(m, __shfl_down(m, 16));  // lanes 0..15: max over 64 anchors
            mx[nt] = m;
        }
    };

    if (tid < 192) anch[tid] = anchors[tid];
    __syncthreads();
    geom(base + 0, 0);
    __syncthreads();  // xs*[0] ready

    for (int q = 0; q < P_PTS; ++q) {
        const int b = q & 1;
        float dmx[4], amx[4];

        fill(xsd[b][frow]);            // d-embedding for point q
        __syncthreads();               // E(d) ready
        if (q + 1 < P_PTS) geom(base + q + 1, b ^ 1);  // overlaps d-GEMM
        gemm_max(wdp, dmx);
        __syncthreads();               // E(d) consumed

        fill(xsa[b][frow]);            // a-embedding for point q
        __syncthreads();               // E(a) ready
        gemm_max(wap, amx);

        if (lane < 16) {
            #pragma unroll
            for (int nt = 0; nt < 4; ++nt) {
                const int col = wave * 64 + nt * 16 + l16;
                out[(base + q) * HH + col] = dmx[nt] + amx[nt] + bias[nt];
            }
        }
        __syncthreads();               // E(a) consumed; safe to refill
    }
}

extern "C" void kernel_launch(void* const* d_in, const int* in_sizes, int n_in,
                              void* d_out, int out_size, void* d_ws, size_t ws_size,
                              hipStream_t stream) {
    const float* points  = (const float*)d_in[0];
    const float* anchors = (const float*)d_in[1];
    // d_in[2] = cor_score: unused by the reference
    const float* Wa = (const float*)d_in[3];
    const float* ba = (const float*)d_in[4];
    const float* Wd = (const float*)d_in[5];
    const float* bd = (const float*)d_in[6];

    unsigned short* wbf = (unsigned short*)d_ws;  // 256 KB: Wd|Wa bf16

    hipLaunchKernelGGL(prep_w_kernel, dim3(256), dim3(256), 0, stream, Wa, Wd, wbf);
    hipLaunchKernelGGL(cgse_main, dim3(NPTS / P_PTS), dim3(256), 0, stream,
                       points, anchors, wbf, ba, bd, (float*)d_out);
}

// Round 5
// 149.266 us; speedup vs baseline: 2.0589x; 2.0589x over previous
//
#include <hip/hip_runtime.h>
#include <hip/hip_bf16.h>
#include <math.h>

// CrossGeometricStructureEmbedding, round 5.
// R3/R4 post-mortem: launch_bounds(256,3) with ~200-reg demand => accumulator
// spill (FETCH/WRITE blowup). Fix: HALVE per-wave demand instead of capping a
// too-big loop. Each wave owns 32 output cols: W-strip 64 regs + acc[4][2]=32
// => demand ~140 < 170 cap => 3 waves/EU without spill.
// Grid = 2 types x 2 col-halves x 512 point-groups (P_PTS=8) = 2048 blocks.
// E tile (64x256 bf16, 32 KB) is XOR-swizzled (chunk ^ row&7): uniform-bank
// b128 fill writes (structural-min 8/bank) and 2-way (free) A-frag reads.
// Epilogue: per-col max via in-reg fmax + shfl(32,16), unsafeAtomicAdd into
// zeroed out; d-type blocks carry (ba+bd).

typedef __attribute__((ext_vector_type(8))) short short8;
typedef __attribute__((ext_vector_type(4))) float f32x4;
typedef __attribute__((ext_vector_type(4))) unsigned int uint4v;

#define HH 256
#define P_PTS 8
#define NPTS 4096

__device__ __forceinline__ unsigned short f2bf(float f) {
    union { float f; unsigned int u; } v; v.f = f;
    unsigned int r = v.u + 0x7fffu + ((v.u >> 16) & 1u);  // RNE
    return (unsigned short)(r >> 16);
}

__device__ __forceinline__ unsigned int pack_sc(float s, float c) {
    union { __hip_bfloat162 h; unsigned int u; } v;
    v.h = __float22bfloat162_rn(make_float2(s, c));  // low = sin, high = cos
    return v.u;
}

__global__ __launch_bounds__(256)
void prep_w_kernel(const float* __restrict__ Wa, const float* __restrict__ Wd,
                   unsigned short* __restrict__ wbf) {
    int i = blockIdx.x * 256 + threadIdx.x;
    if (i < HH * HH) {
        wbf[i] = f2bf(Wd[i]);             // [0, 65536): Wd bf16
        wbf[HH * HH + i] = f2bf(Wa[i]);   // [65536, 131072): Wa bf16
    }
}

// E chunk addressing: 16B chunks, 32 per row; chunk c of row r lives at
// shorts offset r*256 + ((c ^ (r & 7)) << 3).
__device__ __forceinline__ int eoff(int r, int c) {
    return r * HH + ((c ^ (r & 7)) << 3);
}

__global__ __launch_bounds__(256, 3)
void cgse_main(const float* __restrict__ points,
               const float* __restrict__ anchors,
               const unsigned short* __restrict__ wbf,
               const float* __restrict__ ba,
               const float* __restrict__ bd,
               float* __restrict__ out) {
    __shared__ __align__(16) unsigned short E[64 * HH];  // 32 KB, xor-swizzled
    __shared__ float xs[2][64];
    __shared__ float anch[192];

    const int tid = threadIdx.x;
    const int wave = tid >> 6, lane = tid & 63;
    const int quad = lane >> 4, l16 = lane & 15;
    const int type = blockIdx.x & 1;            // 0 = d (Wd), 1 = a (Wa)
    const int half = (blockIdx.x >> 1) & 1;     // which 128-col half
    const int base = (blockIdx.x >> 2) * P_PTS;
    const int colw = half * 128 + wave * 32;    // this wave's 32-col strip base

    // ---- W strip into registers: 2 nt x 8 ks x short8 = 64 VGPRs
    const unsigned short* W = wbf + type * (HH * HH);
    short8 bw[2][8];
    #pragma unroll
    for (int nt = 0; nt < 2; ++nt) {
        const unsigned short* wb = W + (colw + nt * 16 + l16) * HH + quad * 8;
        #pragma unroll
        for (int ks = 0; ks < 8; ++ks)
            bw[nt][ks] = *(const short8*)(wb + ks * 32);
    }

    // biases: only d-type blocks add (ba + bd); a-type adds raw max
    float bias[2];
    #pragma unroll
    for (int nt = 0; nt < 2; ++nt) {
        const int c = colw + nt * 16 + l16;
        bias[nt] = (type == 0) ? (ba[c] + bd[c]) : 0.0f;
    }

    // div_term split: pair index i = ks*16 + quad*4 + j
    // dt0[j] = 10000^(-(quad*4+j)/128); rk[ks] = 10000^(-ks/8)
    float dt0[4];
    #pragma unroll
    for (int j = 0; j < 4; ++j)
        dt0[j] = __expf(-(float)(quad * 4 + j) * 0.0719557841560639f);
    const float rk[8] = {1.0f, 0.31622776601683794f, 0.1f, 0.031622776601683794f,
                         0.01f, 0.0031622776601683794f, 0.001f, 0.00031622776601683794f};

    auto geom = [&](int pn, int slot) {
        if (tid < 64) {
            const float px = points[pn * 3 + 0], py = points[pn * 3 + 1], pz = points[pn * 3 + 2];
            const int k = tid;
            const float r1x = px - anch[k * 3 + 0];
            const float r1y = py - anch[k * 3 + 1];
            const float r1z = pz - anch[k * 3 + 2];
            float v;
            if (type == 0) {
                v = sqrtf(r1x * r1x + r1y * r1y + r1z * r1z) * 5.0f;  // /SIGMA_D
            } else {
                const int k2 = (k + 1) & 63;  // roll(-1)
                const float r2x = px - anch[k2 * 3 + 0];
                const float r2y = py - anch[k2 * 3 + 1];
                const float r2z = pz - anch[k2 * 3 + 2];
                const float cx = r1y * r2z - r1z * r2y;
                const float cy = r1z * r2x - r1x * r2z;
                const float cz = r1x * r2y - r1y * r2x;
                const float sv = sqrtf(cx * cx + cy * cy + cz * cz);
                const float cv = r1x * r2x + r1y * r2y + r1z * r2z;
                v = atan2f(sv, cv) * 3.8197186342054885f;  // *180/(15*pi)
            }
            xs[slot][k] = v;
        }
    };

    const int frow = wave * 16 + l16;  // row this thread fills

    if (tid < 192) anch[tid] = anchors[tid];
    __syncthreads();
    geom(base + 0, 0);
    __syncthreads();  // xs[0] ready

    for (int q = 0; q < P_PTS; ++q) {
        const int b = q & 1;

        // ---- fill E with point q's embedding (swizzled chunks)
        {
            const float xv = xs[b][frow];
            float xq[4];
            #pragma unroll
            for (int j = 0; j < 4; ++j) xq[j] = xv * dt0[j];
            #pragma unroll
            for (int ks = 0; ks < 8; ++ks) {
                uint4v w;
                #pragma unroll
                for (int j = 0; j < 4; ++j) {
                    float s, c;
                    __sincosf(xq[j] * rk[ks], &s, &c);
                    w[j] = pack_sc(s, c);
                }
                *(uint4v*)&E[eoff(frow, ks * 4 + quad)] = w;
            }
        }
        __syncthreads();  // E ready

        if (q + 1 < P_PTS) geom(base + q + 1, b ^ 1);  // overlaps GEMM below

        f32x4 acc[4][2];
        #pragma unroll
        for (int mt = 0; mt < 4; ++mt)
            #pragma unroll
            for (int nt = 0; nt < 2; ++nt)
                acc[mt][nt] = (f32x4){0.f, 0.f, 0.f, 0.f};

        #pragma unroll
        for (int ks = 0; ks < 8; ++ks) {
            #pragma unroll
            for (int mt = 0; mt < 4; ++mt) {
                const short8 afr = *(const short8*)&E[eoff(mt * 16 + l16, ks * 4 + quad)];
                #pragma unroll
                for (int nt = 0; nt < 2; ++nt)
                    acc[mt][nt] = __builtin_amdgcn_mfma_f32_16x16x32_bf16(
                        afr, bw[nt][ks], acc[mt][nt], 0, 0, 0);
            }
        }

        #pragma unroll
        for (int nt = 0; nt < 2; ++nt) {
            float m = fmaxf(fmaxf(acc[0][nt][0], acc[0][nt][1]),
                            fmaxf(acc[0][nt][2], acc[0][nt][3]));
            #pragma unroll
            for (int mt = 1; mt < 4; ++mt)
                m = fmaxf(m, fmaxf(fmaxf(acc[mt][nt][0], acc[mt][nt][1]),
                                   fmaxf(acc[mt][nt][2], acc[mt][nt][3])));
            m = fmaxf(m, __shfl_down(m, 32));
            m = fmaxf(m, __shfl_down(m, 16));  // lanes 0..15: max over 64 anchors
            if (lane < 16)
                unsafeAtomicAdd(&out[(base + q) * HH + colw + nt * 16 + l16],
                                m + bias[nt]);
        }
        __syncthreads();  // E consumed; safe to refill next q
    }
}

extern "C" void kernel_launch(void* const* d_in, const int* in_sizes, int n_in,
                              void* d_out, int out_size, void* d_ws, size_t ws_size,
                              hipStream_t stream) {
    const float* points  = (const float*)d_in[0];
    const float* anchors = (const float*)d_in[1];
    // d_in[2] = cor_score: unused by the reference
    const float* Wa = (const float*)d_in[3];
    const float* ba = (const float*)d_in[4];
    const float* Wd = (const float*)d_in[5];
    const float* bd = (const float*)d_in[6];

    unsigned short* wbf = (unsigned short*)d_ws;  // 256 KB: Wd|Wa bf16

    hipMemsetAsync(d_out, 0, (size_t)NPTS * HH * sizeof(float), stream);
    hipLaunchKernelGGL(prep_w_kernel, dim3(256), dim3(256), 0, stream, Wa, Wd, wbf);
    hipLaunchKernelGGL(cgse_main, dim3(4 * (NPTS / P_PTS)), dim3(256), 0, stream,
                       points, anchors, wbf, ba, bd, (float*)d_out);
}